// Round 1
// baseline (326.469 us; speedup 1.0000x reference)
//
#include <hip/hip_runtime.h>
#include <math.h>

#define B_  32
#define S_  512
#define D_  256
#define H_  4
#define DK_ 64

// ---------------------------------------------------------------------------
// Generic tiled f32 GEMM: out[M,N] = A[M,K] * W[N,K]^T + bias[N]
// BM=BN=BK=64, 256 threads, 4x4 micro-tile per thread. LDS padded to 65.
// ---------------------------------------------------------------------------
__global__ __launch_bounds__(256) void gemm_abt_kernel(
    const float* __restrict__ A, const float* __restrict__ W,
    const float* __restrict__ bias, float* __restrict__ out,
    int M, int N, int K) {
  __shared__ float As[64][65];
  __shared__ float Ws[64][65];
  const int tid = threadIdx.x;
  const int tx = tid & 15, ty = tid >> 4;
  const int m0 = blockIdx.x * 64, n0 = blockIdx.y * 64;
  float acc[4][4] = {};
  for (int k0 = 0; k0 < K; k0 += 64) {
#pragma unroll
    for (int i = 0; i < 4; ++i) {
      int idx = tid + i * 256;                 // float4 index within 64x64 tile
      int r = idx >> 4, c = (idx & 15) << 2;
      float4 a4 = *reinterpret_cast<const float4*>(A + (size_t)(m0 + r) * K + k0 + c);
      As[r][c] = a4.x; As[r][c + 1] = a4.y; As[r][c + 2] = a4.z; As[r][c + 3] = a4.w;
      float4 w4 = *reinterpret_cast<const float4*>(W + (size_t)(n0 + r) * K + k0 + c);
      Ws[r][c] = w4.x; Ws[r][c + 1] = w4.y; Ws[r][c + 2] = w4.z; Ws[r][c + 3] = w4.w;
    }
    __syncthreads();
#pragma unroll 8
    for (int kk = 0; kk < 64; ++kk) {
      float a[4], w[4];
#pragma unroll
      for (int i = 0; i < 4; ++i) a[i] = As[ty * 4 + i][kk];
#pragma unroll
      for (int j = 0; j < 4; ++j) w[j] = Ws[tx * 4 + j][kk];
#pragma unroll
      for (int i = 0; i < 4; ++i)
#pragma unroll
        for (int j = 0; j < 4; ++j) acc[i][j] += a[i] * w[j];
    }
    __syncthreads();
  }
#pragma unroll
  for (int i = 0; i < 4; ++i) {
    int r = m0 + ty * 4 + i;
#pragma unroll
    for (int j = 0; j < 4; ++j) {
      int c = n0 + tx * 4 + j;
      float vv = acc[i][j];
      if (bias) vv += bias[c];
      out[(size_t)r * N + c] = vv;
    }
  }
}

// ---------------------------------------------------------------------------
// Scores: attn[b,s,h,t] = (qs[b,s,h,:] . ks[b,t,h,:]) / 8 for lower-tri tiles.
// qs/ks layout from proj kernel: [B, S, H, DK] (row stride H*DK for fixed h).
// Output written directly into d_out attn region at [B,S,H,S] layout.
// Grid: (36 lower-tri tile pairs, H, B). Tile 64x64, K=DK=64 single pass.
// ---------------------------------------------------------------------------
__global__ __launch_bounds__(256) void scores_kernel(
    const float* __restrict__ qs, const float* __restrict__ ks,
    float* __restrict__ attn) {
  const int p = blockIdx.x, h = blockIdx.y, b = blockIdx.z;
  int ts = 0;
  while (((ts + 1) * (ts + 2)) / 2 <= p) ++ts;
  const int tt = p - (ts * (ts + 1)) / 2;
  const int s0 = ts * 64, t0 = tt * 64;
  const float* qb = qs + (size_t)b * S_ * H_ * DK_ + h * DK_;     // row stride H_*DK_
  const float* kb = ks + (size_t)b * S_ * H_ * DK_ + h * DK_;
  float* ob = attn + (size_t)b * S_ * H_ * S_ + (size_t)h * S_;   // row stride H_*S_

  __shared__ float Qs[64][65];
  __shared__ float Ks[64][65];
  const int tid = threadIdx.x;
  const int tx = tid & 15, ty = tid >> 4;
#pragma unroll
  for (int i = 0; i < 4; ++i) {
    int idx = tid + i * 256;
    int r = idx >> 4, c = (idx & 15) << 2;
    float4 q4 = *reinterpret_cast<const float4*>(qb + (size_t)(s0 + r) * (H_ * DK_) + c);
    Qs[r][c] = q4.x; Qs[r][c + 1] = q4.y; Qs[r][c + 2] = q4.z; Qs[r][c + 3] = q4.w;
    float4 k4 = *reinterpret_cast<const float4*>(kb + (size_t)(t0 + r) * (H_ * DK_) + c);
    Ks[r][c] = k4.x; Ks[r][c + 1] = k4.y; Ks[r][c + 2] = k4.z; Ks[r][c + 3] = k4.w;
  }
  __syncthreads();
  float acc[4][4] = {};
#pragma unroll 8
  for (int kk = 0; kk < 64; ++kk) {
    float a[4], w[4];
#pragma unroll
    for (int i = 0; i < 4; ++i) a[i] = Qs[ty * 4 + i][kk];
#pragma unroll
    for (int j = 0; j < 4; ++j) w[j] = Ks[tx * 4 + j][kk];
#pragma unroll
    for (int i = 0; i < 4; ++i)
#pragma unroll
      for (int j = 0; j < 4; ++j) acc[i][j] += a[i] * w[j];
  }
#pragma unroll
  for (int i = 0; i < 4; ++i) {
    int s = s0 + ty * 4 + i;
#pragma unroll
    for (int j = 0; j < 4; ++j) {
      ob[(size_t)s * (H_ * S_) + t0 + tx * 4 + j] = acc[i][j] * 0.125f;
    }
  }
}

// ---------------------------------------------------------------------------
// Softmax in place on attn rows [b,s,h,:]: one wave per row; causal (t<=s).
// Writes zeros above the diagonal (covers poisoned / never-written tiles).
// ---------------------------------------------------------------------------
__global__ __launch_bounds__(256) void softmax_kernel(float* __restrict__ attn) {
  const int gw = blockIdx.x * 4 + (threadIdx.x >> 6);   // row id = ((b*S+s)*H+h)
  const int lane = threadIdx.x & 63;
  const int s = (gw >> 2) & (S_ - 1);
  float* row = attn + (size_t)gw * S_;
  float v[8];
  float m = -INFINITY;
#pragma unroll
  for (int i = 0; i < 8; ++i) {
    int t = lane + i * 64;
    v[i] = (t <= s) ? row[t] : -INFINITY;
    m = fmaxf(m, v[i]);
  }
#pragma unroll
  for (int off = 32; off > 0; off >>= 1) m = fmaxf(m, __shfl_xor(m, off));
  float l = 0.f;
#pragma unroll
  for (int i = 0; i < 8; ++i) {
    int t = lane + i * 64;
    v[i] = (t <= s) ? __expf(v[i] - m) : 0.f;
    l += v[i];
  }
#pragma unroll
  for (int off = 32; off > 0; off >>= 1) l += __shfl_xor(l, off);
  const float inv = 1.f / l;
#pragma unroll
  for (int i = 0; i < 8; ++i) row[lane + i * 64] = v[i] * inv;
}

// ---------------------------------------------------------------------------
// heads-mean: mh[b,s,k] = (1/H) sum_h sum_t attn[b,s,h,t] * vs[b,t,k]
// One block per (s-tile, b); loops lower-tri t-tiles, h inside.
// ---------------------------------------------------------------------------
__global__ __launch_bounds__(256) void heads_kernel(
    const float* __restrict__ attn, const float* __restrict__ vs,
    float* __restrict__ mh) {
  const int st = blockIdx.x, b = blockIdx.y;
  const int s0 = st * 64;
  __shared__ float At[64][65];
  __shared__ float Vt[64][65];
  const int tid = threadIdx.x;
  const int tx = tid & 15, ty = tid >> 4;
  float acc[4][4] = {};
  const float* vb = vs + (size_t)b * S_ * DK_;
  for (int tt = 0; tt <= st; ++tt) {
    const int t0 = tt * 64;
#pragma unroll
    for (int i = 0; i < 4; ++i) {
      int idx = tid + i * 256;
      int r = idx >> 4, c = (idx & 15) << 2;
      float4 v4 = *reinterpret_cast<const float4*>(vb + (size_t)(t0 + r) * DK_ + c);
      Vt[r][c] = v4.x; Vt[r][c + 1] = v4.y; Vt[r][c + 2] = v4.z; Vt[r][c + 3] = v4.w;
    }
    for (int h = 0; h < H_; ++h) {
      const float* ab = attn + (size_t)b * S_ * H_ * S_ + (size_t)h * S_;
#pragma unroll
      for (int i = 0; i < 4; ++i) {
        int idx = tid + i * 256;
        int r = idx >> 4, c = (idx & 15) << 2;
        float4 a4 = *reinterpret_cast<const float4*>(ab + (size_t)(s0 + r) * (H_ * S_) + t0 + c);
        At[r][c] = a4.x; At[r][c + 1] = a4.y; At[r][c + 2] = a4.z; At[r][c + 3] = a4.w;
      }
      __syncthreads();
#pragma unroll 8
      for (int kk = 0; kk < 64; ++kk) {
        float a[4], w[4];
#pragma unroll
        for (int i = 0; i < 4; ++i) a[i] = At[ty * 4 + i][kk];
#pragma unroll
        for (int j = 0; j < 4; ++j) w[j] = Vt[kk][tx * 4 + j];
#pragma unroll
        for (int i = 0; i < 4; ++i)
#pragma unroll
          for (int j = 0; j < 4; ++j) acc[i][j] += a[i] * w[j];
      }
      __syncthreads();
    }
  }
  float* mb = mh + (size_t)b * S_ * DK_;
#pragma unroll
  for (int i = 0; i < 4; ++i) {
    int s = s0 + ty * 4 + i;
#pragma unroll
    for (int j = 0; j < 4; ++j) {
      mb[(size_t)s * DK_ + tx * 4 + j] = acc[i][j] * 0.25f;
    }
  }
}

// ---------------------------------------------------------------------------
extern "C" void kernel_launch(void* const* d_in, const int* in_sizes, int n_in,
                              void* d_out, int out_size, void* d_ws, size_t ws_size,
                              hipStream_t stream) {
  (void)in_sizes; (void)n_in; (void)out_size; (void)ws_size;
  const float* q  = (const float*)d_in[0];
  const float* k  = (const float*)d_in[1];
  const float* v  = (const float*)d_in[2];
  // d_in[3] = causal mask (statically known; unused)
  const float* Wq = (const float*)d_in[4];
  const float* bq = (const float*)d_in[5];
  const float* Wk = (const float*)d_in[6];
  const float* bk = (const float*)d_in[7];
  const float* Wv = (const float*)d_in[8];
  const float* bv = (const float*)d_in[9];
  const float* Wh = (const float*)d_in[10];

  float* out  = (float*)d_out;                       // [B,S,D]
  float* attn = out + (size_t)B_ * S_ * D_;          // [B,S,H,S]

  float* ws  = (float*)d_ws;                         // 40 MB scratch
  float* qs  = ws;                                   // [B,S,H,DK]
  float* ks  = qs  + (size_t)B_ * S_ * H_ * DK_;     // [B,S,H,DK]
  float* vsp = ks  + (size_t)B_ * S_ * H_ * DK_;     // [B,S,DK]
  float* mh  = vsp + (size_t)B_ * S_ * DK_;          // [B,S,DK]

  const int M = B_ * S_;  // 16384

  // Projections: qs = q.Wq^T + bq ; ks = k.Wk^T + bk ; vs = v.Wv^T + bv
  gemm_abt_kernel<<<dim3(M / 64, (H_ * DK_) / 64), 256, 0, stream>>>(q, Wq, bq, qs, M, H_ * DK_, D_);
  gemm_abt_kernel<<<dim3(M / 64, (H_ * DK_) / 64), 256, 0, stream>>>(k, Wk, bk, ks, M, H_ * DK_, D_);
  gemm_abt_kernel<<<dim3(M / 64, DK_ / 64), 256, 0, stream>>>(v, Wv, bv, vsp, M, DK_, D_);

  // Causal scores into d_out attn region (lower-tri tiles only), then softmax.
  scores_kernel<<<dim3(36, H_, B_), 256, 0, stream>>>(qs, ks, attn);
  softmax_kernel<<<dim3((B_ * S_ * H_) / 4), 256, 0, stream>>>(attn);

  // heads-mean, then output projection.
  heads_kernel<<<dim3(S_ / 64, B_), 256, 0, stream>>>(attn, vsp, mh);
  gemm_abt_kernel<<<dim3(M / 64, D_ / 64), 256, 0, stream>>>(mh, Wh, nullptr, out, M, D_, DK_);
}

// Round 2
// 175.666 us; speedup vs baseline: 1.8585x; 1.8585x over previous
//
#include <hip/hip_runtime.h>
#include <math.h>

#define B_  32
#define S_  512
#define D_  256
#define H_  4
#define DK_ 64

typedef float  f32x4 __attribute__((ext_vector_type(4)));
typedef short  s16x8 __attribute__((ext_vector_type(8)));
typedef unsigned short u16x4 __attribute__((ext_vector_type(4)));

#define MFMA_BF16(a, b, c) __builtin_amdgcn_mfma_f32_16x16x32_bf16((a), (b), (c), 0, 0, 0)

__device__ __forceinline__ unsigned short f2bf(float x) {
  unsigned int u = __float_as_uint(x);
  unsigned int r = (u + 0x7FFFu + ((u >> 16) & 1u)) >> 16;
  return (unsigned short)r;
}

__device__ __forceinline__ s16x8 cvt8(const float* p) {
  float4 a = *(const float4*)p;
  float4 b = *(const float4*)(p + 4);
  s16x8 r;
  r[0] = (short)f2bf(a.x); r[1] = (short)f2bf(a.y);
  r[2] = (short)f2bf(a.z); r[3] = (short)f2bf(a.w);
  r[4] = (short)f2bf(b.x); r[5] = (short)f2bf(b.y);
  r[6] = (short)f2bf(b.z); r[7] = (short)f2bf(b.w);
  return r;
}

// ---------------------------------------------------------------------------
// Convert all weights to bf16 into one contiguous buffer:
// rows 0..255: Wq[h*64+dk][256]; 256..511: Wk; 512..575: Wv[dk][256];
// then Wh flat at elem offset 147456 ([256][64]).
// ---------------------------------------------------------------------------
__global__ void wconv_kernel(const float* __restrict__ Wq, const float* __restrict__ Wk,
                             const float* __restrict__ Wv, const float* __restrict__ Wh,
                             unsigned short* __restrict__ out) {
  int i = blockIdx.x * 256 + threadIdx.x;  // 163840 total
  float v;
  if (i < 65536)        v = Wq[i];
  else if (i < 131072)  v = Wk[i - 65536];
  else if (i < 147456)  v = Wv[i - 131072];
  else                  v = Wh[i - 147456];
  out[i] = f2bf(v);
}

// ---------------------------------------------------------------------------
// Fused QKV projection, bf16 MFMA, no LDS.
// y==0: qs[b][h][s][dk] = q.Wq^T + bq   (bf16 out, head-major)
// y==1: ks likewise
// y==2: vst[b][dk][t]   = (v.Wv^T + bv)^T  (bf16, pre-transposed for PV)
// Block: 64 rows of M=B*S; 4 waves; wave w owns rows [w*16, w*16+16).
// ---------------------------------------------------------------------------
__global__ __launch_bounds__(256) void proj_kernel(
    const float* __restrict__ q, const float* __restrict__ k, const float* __restrict__ v,
    const unsigned short* __restrict__ Wb,
    const float* __restrict__ bq, const float* __restrict__ bk, const float* __restrict__ bv,
    unsigned short* __restrict__ qs, unsigned short* __restrict__ ks,
    unsigned short* __restrict__ vst) {
  const int y = blockIdx.y;
  const int m0 = blockIdx.x * 64;
  const int b = m0 >> 9, s0 = m0 & (S_ - 1);
  const int tid = threadIdx.x, w = tid >> 6, l = tid & 63;
  const int lr = l & 15, lg = l >> 4;
  const float* src = (y == 0) ? q : (y == 1) ? k : v;
  const float* abase = src + (size_t)(m0 + w * 16 + lr) * D_;

  if (y < 2) {
    const int wrow0 = y * 256;
    f32x4 acc[4][4] = {};
    for (int k0 = 0; k0 < D_; k0 += 32) {
      s16x8 af = cvt8(abase + k0 + 8 * lg);
#pragma unroll
      for (int h = 0; h < 4; ++h) {
#pragma unroll
        for (int ns = 0; ns < 4; ++ns) {
          s16x8 wf = *(const s16x8*)(Wb + (size_t)(wrow0 + h * 64 + ns * 16 + lr) * D_ + k0 + 8 * lg);
          acc[h][ns] = MFMA_BF16(af, wf, acc[h][ns]);
        }
      }
    }
    const float* bias = (y == 0) ? bq : bk;
    unsigned short* dst = (y == 0) ? qs : ks;
#pragma unroll
    for (int h = 0; h < 4; ++h) {
#pragma unroll
      for (int ns = 0; ns < 4; ++ns) {
        int dk = ns * 16 + lr;
        float bb = bias[h * 64 + dk];
#pragma unroll
        for (int i = 0; i < 4; ++i) {
          int s = s0 + w * 16 + lg * 4 + i;
          dst[(((size_t)b * H_ + h) * S_ + s) * DK_ + dk] = f2bf(acc[h][ns][i] + bb);
        }
      }
    }
  } else {
    f32x4 acc[4] = {};
    for (int k0 = 0; k0 < D_; k0 += 32) {
      s16x8 af = cvt8(abase + k0 + 8 * lg);
#pragma unroll
      for (int ns = 0; ns < 4; ++ns) {
        s16x8 wf = *(const s16x8*)(Wb + (size_t)(512 + ns * 16 + lr) * D_ + k0 + 8 * lg);
        acc[ns] = MFMA_BF16(af, wf, acc[ns]);
      }
    }
#pragma unroll
    for (int ns = 0; ns < 4; ++ns) {
      int dk = ns * 16 + lr;
      float bb = bv[dk];
      u16x4 pk;
#pragma unroll
      for (int i = 0; i < 4; ++i) pk[i] = f2bf(acc[ns][i] + bb);
      int t = s0 + w * 16 + lg * 4;
      *(u16x4*)(vst + ((size_t)b * DK_ + dk) * S_ + t) = pk;
    }
  }
}

// ---------------------------------------------------------------------------
// Zero-fill strict-upper causal tiles of attn [B,S,H,S].
// ---------------------------------------------------------------------------
__global__ void zerofill_kernel(float* __restrict__ attn) {
  int p = blockIdx.x, h = blockIdx.y, b = blockIdx.z;
  int st = 0, rem = p;
  while (rem >= 7 - st) { rem -= 7 - st; st++; }
  int tt = st + 1 + rem;
  int s0 = st * 64, t0 = tt * 64;
  int r = threadIdx.x >> 4, c4 = (threadIdx.x & 15) * 4;
  f32x4 z = {};
#pragma unroll
  for (int i = 0; i < 4; ++i) {
    *(f32x4*)(attn + (((size_t)b * S_ + s0 + r + i * 16) * H_ + h) * S_ + t0 + c4) = z;
  }
}

// ---------------------------------------------------------------------------
// Fused scores + softmax + attn-write + PV.  Grid (s-tile, h, b), 4 waves.
// Pass 1: QK^T MFMA + online per-lane max/sum over causal t-tiles, then one
// cross-lane (16-lane group) merge.  Pass 2: recompute QK^T, write normalized
// P (f32) to attn, round to bf16 via per-wave LDS, PV MFMA from vst.
// ---------------------------------------------------------------------------
__global__ __launch_bounds__(256) void attn_kernel(
    const unsigned short* __restrict__ qs, const unsigned short* __restrict__ ks,
    const unsigned short* __restrict__ vst, float* __restrict__ attn,
    float* __restrict__ hh) {
  const int st = blockIdx.x, h = blockIdx.y, b = blockIdx.z;
  const int tid = threadIdx.x, w = tid >> 6, l = tid & 63;
  const int lr = l & 15, lg = l >> 4;
  const int s0 = st * 64;
  __shared__ __align__(16) unsigned short Pb[4][16][72];

  const unsigned short* qb = qs + ((size_t)b * H_ + h) * S_ * DK_;
  const unsigned short* kb = ks + ((size_t)b * H_ + h) * S_ * DK_;
  const unsigned short* vb = vst + (size_t)b * DK_ * S_;

  s16x8 qf0 = *(const s16x8*)(qb + (size_t)(s0 + w * 16 + lr) * DK_ + 8 * lg);
  s16x8 qf1 = *(const s16x8*)(qb + (size_t)(s0 + w * 16 + lr) * DK_ + 32 + 8 * lg);

  float m[4], lsum[4];
#pragma unroll
  for (int i = 0; i < 4; ++i) { m[i] = -1e30f; lsum[i] = 0.f; }

  // ---- pass 1: online softmax stats ----
  for (int tt = 0; tt <= st; ++tt) {
    const int t0 = tt * 64;
    float sc[4][4];
#pragma unroll
    for (int ts = 0; ts < 4; ++ts) {
      const unsigned short* kr = kb + (size_t)(t0 + ts * 16 + lr) * DK_;
      s16x8 kf0 = *(const s16x8*)(kr + 8 * lg);
      s16x8 kf1 = *(const s16x8*)(kr + 32 + 8 * lg);
      f32x4 acc = {};
      acc = MFMA_BF16(qf0, kf0, acc);
      acc = MFMA_BF16(qf1, kf1, acc);
      int tg = t0 + ts * 16 + lr;
#pragma unroll
      for (int i = 0; i < 4; ++i) {
        int sg = s0 + w * 16 + lg * 4 + i;
        float vsc = acc[i] * 0.125f;
        sc[ts][i] = (tg > sg) ? -1e30f : vsc;
      }
    }
#pragma unroll
    for (int i = 0; i < 4; ++i) {
      float tmax = fmaxf(fmaxf(sc[0][i], sc[1][i]), fmaxf(sc[2][i], sc[3][i]));
      float mn = fmaxf(m[i], tmax);
      float sscale = __expf(m[i] - mn);
      float add = __expf(sc[0][i] - mn) + __expf(sc[1][i] - mn) +
                  __expf(sc[2][i] - mn) + __expf(sc[3][i] - mn);
      lsum[i] = lsum[i] * sscale + add;
      m[i] = mn;
    }
  }
  // ---- cross-lane merge within 16-lane groups ----
#pragma unroll
  for (int off = 1; off < 16; off <<= 1) {
#pragma unroll
    for (int i = 0; i < 4; ++i) {
      float om = __shfl_xor(m[i], off);
      float ol = __shfl_xor(lsum[i], off);
      float mn = fmaxf(m[i], om);
      lsum[i] = lsum[i] * __expf(m[i] - mn) + ol * __expf(om - mn);
      m[i] = mn;
    }
  }
  float inv[4];
#pragma unroll
  for (int i = 0; i < 4; ++i) inv[i] = 1.0f / lsum[i];

  // ---- pass 2: P write + PV ----
  f32x4 oacc[4] = {};
  for (int tt = 0; tt <= st; ++tt) {
    const int t0 = tt * 64;
#pragma unroll
    for (int ts = 0; ts < 4; ++ts) {
      const unsigned short* kr = kb + (size_t)(t0 + ts * 16 + lr) * DK_;
      s16x8 kf0 = *(const s16x8*)(kr + 8 * lg);
      s16x8 kf1 = *(const s16x8*)(kr + 32 + 8 * lg);
      f32x4 acc = {};
      acc = MFMA_BF16(qf0, kf0, acc);
      acc = MFMA_BF16(qf1, kf1, acc);
      int tg = t0 + ts * 16 + lr;
#pragma unroll
      for (int i = 0; i < 4; ++i) {
        int sg = s0 + w * 16 + lg * 4 + i;
        float p = (tg <= sg) ? __expf(acc[i] * 0.125f - m[i]) * inv[i] : 0.f;
        attn[(((size_t)b * S_ + sg) * H_ + h) * S_ + tg] = p;
        Pb[w][lg * 4 + i][ts * 16 + lr] = f2bf(p);
      }
    }
    asm volatile("s_waitcnt lgkmcnt(0)" ::: "memory");
    __builtin_amdgcn_sched_barrier(0);
    s16x8 pa0 = *(const s16x8*)(&Pb[w][lr][8 * lg]);
    s16x8 pa1 = *(const s16x8*)(&Pb[w][lr][32 + 8 * lg]);
#pragma unroll
    for (int ds = 0; ds < 4; ++ds) {
      const unsigned short* vr = vb + (size_t)(ds * 16 + lr) * S_ + t0;
      s16x8 vf0 = *(const s16x8*)(vr + 8 * lg);
      s16x8 vf1 = *(const s16x8*)(vr + 32 + 8 * lg);
      oacc[ds] = MFMA_BF16(pa0, vf0, oacc[ds]);
      oacc[ds] = MFMA_BF16(pa1, vf1, oacc[ds]);
    }
  }
#pragma unroll
  for (int ds = 0; ds < 4; ++ds) {
#pragma unroll
    for (int i = 0; i < 4; ++i) {
      int s = s0 + w * 16 + lg * 4 + i;
      hh[(((size_t)b * H_ + h) * S_ + s) * DK_ + ds * 16 + lr] = oacc[ds][i];
    }
  }
}

// ---------------------------------------------------------------------------
// mh[b][s][dk] = 0.25 * sum_h hh[b][h][s][dk]  (bf16 out)
// ---------------------------------------------------------------------------
__global__ void mean_kernel(const float* __restrict__ hh, unsigned short* __restrict__ mh) {
  int idx = blockIdx.x * 256 + threadIdx.x;   // over B*S*DK/4 = 262144
  int e4 = idx * 4;
  int b = e4 >> 15;                           // S*DK = 32768
  int rem = e4 & 32767;
  f32x4 sum = {};
#pragma unroll
  for (int h = 0; h < 4; ++h) {
    f32x4 v = *(const f32x4*)(hh + ((size_t)b * H_ + h) * (S_ * DK_) + rem);
    sum += v;
  }
  u16x4 pk;
#pragma unroll
  for (int i = 0; i < 4; ++i) pk[i] = f2bf(sum[i] * 0.25f);
  *(u16x4*)(mh + (size_t)b * (S_ * DK_) + rem) = pk;
}

// ---------------------------------------------------------------------------
// out[m][d] = mh[m][:] . Wh[d][:]  (f32 out), K=64, bf16 MFMA.
// ---------------------------------------------------------------------------
__global__ __launch_bounds__(256) void outproj_kernel(
    const unsigned short* __restrict__ mh, const unsigned short* __restrict__ Whb,
    float* __restrict__ out) {
  const int m0 = blockIdx.x * 64, n0 = blockIdx.y * 64;
  const int tid = threadIdx.x, w = tid >> 6, l = tid & 63;
  const int lr = l & 15, lg = l >> 4;
  s16x8 af0 = *(const s16x8*)(mh + (size_t)(m0 + w * 16 + lr) * DK_ + 8 * lg);
  s16x8 af1 = *(const s16x8*)(mh + (size_t)(m0 + w * 16 + lr) * DK_ + 32 + 8 * lg);
  f32x4 acc[4] = {};
#pragma unroll
  for (int ns = 0; ns < 4; ++ns) {
    const unsigned short* wr = Whb + (size_t)(n0 + ns * 16 + lr) * DK_;
    s16x8 wf0 = *(const s16x8*)(wr + 8 * lg);
    s16x8 wf1 = *(const s16x8*)(wr + 32 + 8 * lg);
    acc[ns] = MFMA_BF16(af0, wf0, acc[ns]);
    acc[ns] = MFMA_BF16(af1, wf1, acc[ns]);
  }
#pragma unroll
  for (int ns = 0; ns < 4; ++ns) {
#pragma unroll
    for (int i = 0; i < 4; ++i) {
      out[(size_t)(m0 + w * 16 + lg * 4 + i) * D_ + n0 + ns * 16 + lr] = acc[ns][i];
    }
  }
}

// ---------------------------------------------------------------------------
extern "C" void kernel_launch(void* const* d_in, const int* in_sizes, int n_in,
                              void* d_out, int out_size, void* d_ws, size_t ws_size,
                              hipStream_t stream) {
  (void)in_sizes; (void)n_in; (void)out_size; (void)ws_size;
  const float* q  = (const float*)d_in[0];
  const float* k  = (const float*)d_in[1];
  const float* v  = (const float*)d_in[2];
  const float* Wq = (const float*)d_in[4];
  const float* bq = (const float*)d_in[5];
  const float* Wk = (const float*)d_in[6];
  const float* bk = (const float*)d_in[7];
  const float* Wv = (const float*)d_in[8];
  const float* bv = (const float*)d_in[9];
  const float* Wh = (const float*)d_in[10];

  float* out  = (float*)d_out;                       // [B,S,D]
  float* attn = out + (size_t)B_ * S_ * D_;          // [B,S,H,S]

  char* ws = (char*)d_ws;
  unsigned short* Wb  = (unsigned short*)ws;                         // 163840 elems
  unsigned short* qs  = (unsigned short*)(ws + 327680);              // [B,H,S,DK] bf16
  unsigned short* ksp = (unsigned short*)(ws + 327680 + 8388608);    // [B,H,S,DK] bf16
  unsigned short* vst = (unsigned short*)(ws + 327680 + 16777216);   // [B,DK,S]  bf16
  float*          hh  = (float*)(ws + 327680 + 18874368);            // [B,H,S,DK] f32
  unsigned short* mh  = (unsigned short*)(ws + 327680 + 35651584);   // [B,S,DK]  bf16

  wconv_kernel<<<640, 256, 0, stream>>>(Wq, Wk, Wv, Wh, Wb);
  proj_kernel<<<dim3(256, 3), 256, 0, stream>>>(q, k, v, Wb, bq, bk, bv, qs, ksp, vst);
  zerofill_kernel<<<dim3(28, H_, B_), 256, 0, stream>>>(attn);
  attn_kernel<<<dim3(8, H_, B_), 256, 0, stream>>>(qs, ksp, vst, attn, hh);
  mean_kernel<<<1024, 256, 0, stream>>>(hh, mh);
  outproj_kernel<<<dim3(256, 4), 256, 0, stream>>>(mh, Wb + 147456, out);
}

// Round 3
// 105.817 us; speedup vs baseline: 3.0852x; 1.6601x over previous
//
#include <hip/hip_runtime.h>
#include <math.h>

#define B_  32
#define S_  512
#define D_  256
#define H_  4
#define DK_ 64

typedef float  f32x4 __attribute__((ext_vector_type(4)));
typedef short  s16x8 __attribute__((ext_vector_type(8)));
typedef unsigned short u16x4 __attribute__((ext_vector_type(4)));

#define MFMA_BF16(a, b, c) __builtin_amdgcn_mfma_f32_16x16x32_bf16((a), (b), (c), 0, 0, 0)
#define GLOAD_LDS16(g, l)                                                      \
  __builtin_amdgcn_global_load_lds(                                            \
      (const __attribute__((address_space(1))) void*)(g),                      \
      (__attribute__((address_space(3))) void*)(l), 16, 0, 0)

__device__ __forceinline__ unsigned short f2bf(float x) {
  unsigned int u = __float_as_uint(x);
  unsigned int r = (u + 0x7FFFu + ((u >> 16) & 1u)) >> 16;
  return (unsigned short)r;
}

__device__ __forceinline__ s16x8 cvt8(const float* p) {
  float4 a = *(const float4*)p;
  float4 b = *(const float4*)(p + 4);
  s16x8 r;
  r[0] = (short)f2bf(a.x); r[1] = (short)f2bf(a.y);
  r[2] = (short)f2bf(a.z); r[3] = (short)f2bf(a.w);
  r[4] = (short)f2bf(b.x); r[5] = (short)f2bf(b.y);
  r[6] = (short)f2bf(b.z); r[7] = (short)f2bf(b.w);
  return r;
}

// ---------------------------------------------------------------------------
// Weights -> bf16: rows 0..255 Wq, 256..511 Wk, 512..575 Wv; Wh at 147456.
// ---------------------------------------------------------------------------
__global__ void wconv_kernel(const float* __restrict__ Wq, const float* __restrict__ Wk,
                             const float* __restrict__ Wv, const float* __restrict__ Wh,
                             unsigned short* __restrict__ out) {
  int i = blockIdx.x * 256 + threadIdx.x;  // 163840 total
  float v;
  if (i < 65536)        v = Wq[i];
  else if (i < 131072)  v = Wk[i - 65536];
  else if (i < 147456)  v = Wv[i - 131072];
  else                  v = Wh[i - 147456];
  out[i] = f2bf(v);
}

// ---------------------------------------------------------------------------
// Fused QKV projection, bf16 MFMA (unchanged from r2).
// ---------------------------------------------------------------------------
__global__ __launch_bounds__(256) void proj_kernel(
    const float* __restrict__ q, const float* __restrict__ k, const float* __restrict__ v,
    const unsigned short* __restrict__ Wb,
    const float* __restrict__ bq, const float* __restrict__ bk, const float* __restrict__ bv,
    unsigned short* __restrict__ qs, unsigned short* __restrict__ ks,
    unsigned short* __restrict__ vst) {
  const int y = blockIdx.y;
  const int m0 = blockIdx.x * 64;
  const int b = m0 >> 9, s0 = m0 & (S_ - 1);
  const int tid = threadIdx.x, w = tid >> 6, l = tid & 63;
  const int lr = l & 15, lg = l >> 4;
  const float* src = (y == 0) ? q : (y == 1) ? k : v;
  const float* abase = src + (size_t)(m0 + w * 16 + lr) * D_;

  if (y < 2) {
    const int wrow0 = y * 256;
    f32x4 acc[4][4] = {};
    for (int k0 = 0; k0 < D_; k0 += 32) {
      s16x8 af = cvt8(abase + k0 + 8 * lg);
#pragma unroll
      for (int h = 0; h < 4; ++h) {
#pragma unroll
        for (int ns = 0; ns < 4; ++ns) {
          s16x8 wf = *(const s16x8*)(Wb + (size_t)(wrow0 + h * 64 + ns * 16 + lr) * D_ + k0 + 8 * lg);
          acc[h][ns] = MFMA_BF16(af, wf, acc[h][ns]);
        }
      }
    }
    const float* bias = (y == 0) ? bq : bk;
    unsigned short* dst = (y == 0) ? qs : ks;
#pragma unroll
    for (int h = 0; h < 4; ++h) {
#pragma unroll
      for (int ns = 0; ns < 4; ++ns) {
        int dk = ns * 16 + lr;
        float bb = bias[h * 64 + dk];
#pragma unroll
        for (int i = 0; i < 4; ++i) {
          int s = s0 + w * 16 + lg * 4 + i;
          dst[(((size_t)b * H_ + h) * S_ + s) * DK_ + dk] = f2bf(acc[h][ns][i] + bb);
        }
      }
    }
  } else {
    f32x4 acc[4] = {};
    for (int k0 = 0; k0 < D_; k0 += 32) {
      s16x8 af = cvt8(abase + k0 + 8 * lg);
#pragma unroll
      for (int ns = 0; ns < 4; ++ns) {
        s16x8 wf = *(const s16x8*)(Wb + (size_t)(512 + ns * 16 + lr) * D_ + k0 + 8 * lg);
        acc[ns] = MFMA_BF16(af, wf, acc[ns]);
      }
    }
#pragma unroll
    for (int ns = 0; ns < 4; ++ns) {
      int dk = ns * 16 + lr;
      float bb = bv[dk];
      u16x4 pk;
#pragma unroll
      for (int i = 0; i < 4; ++i) pk[i] = f2bf(acc[ns][i] + bb);
      int t = s0 + w * 16 + lg * 4;
      *(u16x4*)(vst + ((size_t)b * DK_ + dk) * S_ + t) = pk;
    }
  }
}

// ---------------------------------------------------------------------------
// Fused scores + softmax + attn-write + PV + causal zerofill.
// Grid: 1024 linear; b = n&31, h = (n>>5)&3, st = n>>7 (balanced st per CU).
// K/V tiles double-buffered in LDS via global_load_lds(16B) with XOR swizzle
// (chunk ^= row&7) applied to the global source and the ds_read address.
// ---------------------------------------------------------------------------
__global__ __launch_bounds__(256) void attn_kernel(
    const unsigned short* __restrict__ qs, const unsigned short* __restrict__ ks,
    const unsigned short* __restrict__ vst, float* __restrict__ attn,
    float* __restrict__ hh) {
  const int n = blockIdx.x;
  const int b = n & 31, h = (n >> 5) & 3, st = n >> 7;
  const int tid = threadIdx.x, w = tid >> 6, l = tid & 63;
  const int lr = l & 15, lg = l >> 4;
  const int s0 = st * 64;

  __shared__ __align__(16) unsigned short Kb[2][4096];   // 64 x 64 bf16, swizzled
  __shared__ __align__(16) unsigned short Vb[2][4096];   // [dk][t] bf16, swizzled
  __shared__ __align__(16) unsigned short Pb[4][16][64]; // per-wave P repack

  const unsigned short* qb = qs + ((size_t)b * H_ + h) * S_ * DK_;
  const char* kbase = (const char*)(ks + ((size_t)b * H_ + h) * S_ * DK_);
  const char* vbase = (const char*)(vst + (size_t)b * DK_ * S_);

  // staging: 8KB tile = 2 x (256 threads x 16B); dest linear, source swizzled
  auto stK = [&](int buf, int t0) {
#pragma unroll
    for (int it = 0; it < 2; ++it) {
      int p = it * 4096 + tid * 16;
      int row = p >> 7, c = (p >> 4) & 7;
      GLOAD_LDS16(kbase + (size_t)t0 * 128 + row * 128 + ((c ^ (row & 7)) << 4),
                  (char*)&Kb[buf][0] + p);
    }
  };
  auto stV = [&](int buf, int t0) {
#pragma unroll
    for (int it = 0; it < 2; ++it) {
      int p = it * 4096 + tid * 16;
      int row = p >> 7, c = (p >> 4) & 7;
      GLOAD_LDS16(vbase + (size_t)row * 1024 + t0 * 2 + ((c ^ (row & 7)) << 4),
                  (char*)&Vb[buf][0] + p);
    }
  };
  auto KF = [&](int buf, int row, int c) -> s16x8 {
    return *(const s16x8*)((const char*)&Kb[buf][0] + row * 128 + ((c ^ (row & 7)) << 4));
  };
  auto VF = [&](int buf, int row, int c) -> s16x8 {
    return *(const s16x8*)((const char*)&Vb[buf][0] + row * 128 + ((c ^ (row & 7)) << 4));
  };

  s16x8 qf0 = *(const s16x8*)(qb + (size_t)(s0 + w * 16 + lr) * DK_ + 8 * lg);
  s16x8 qf1 = *(const s16x8*)(qb + (size_t)(s0 + w * 16 + lr) * DK_ + 32 + 8 * lg);

  float m[4], lsum[4];
#pragma unroll
  for (int i = 0; i < 4; ++i) { m[i] = -1e30f; lsum[i] = 0.f; }

  // ---- pass 1: online softmax stats (K staged in LDS, double-buffered) ----
  stK(0, 0);
  __syncthreads();
  for (int tt = 0; tt <= st; ++tt) {
    const int t0 = tt * 64;
    const int cur = tt & 1;
    if (tt < st) stK(cur ^ 1, t0 + 64);
    float sc[4][4];
#pragma unroll
    for (int ts = 0; ts < 4; ++ts) {
      s16x8 kf0 = KF(cur, ts * 16 + lr, lg);
      s16x8 kf1 = KF(cur, ts * 16 + lr, 4 + lg);
      f32x4 acc = {};
      acc = MFMA_BF16(qf0, kf0, acc);
      acc = MFMA_BF16(qf1, kf1, acc);
      int tg = t0 + ts * 16 + lr;
#pragma unroll
      for (int i = 0; i < 4; ++i) {
        int sg = s0 + w * 16 + lg * 4 + i;
        sc[ts][i] = (tg > sg) ? -1e30f : acc[i] * 0.125f;
      }
    }
#pragma unroll
    for (int i = 0; i < 4; ++i) {
      float tmax = fmaxf(fmaxf(sc[0][i], sc[1][i]), fmaxf(sc[2][i], sc[3][i]));
      float mn = fmaxf(m[i], tmax);
      float sscale = __expf(m[i] - mn);
      float add = __expf(sc[0][i] - mn) + __expf(sc[1][i] - mn) +
                  __expf(sc[2][i] - mn) + __expf(sc[3][i] - mn);
      lsum[i] = lsum[i] * sscale + add;
      m[i] = mn;
    }
    __syncthreads();
  }
  // ---- cross-lane merge within 16-lane groups ----
#pragma unroll
  for (int off = 1; off < 16; off <<= 1) {
#pragma unroll
    for (int i = 0; i < 4; ++i) {
      float om = __shfl_xor(m[i], off);
      float ol = __shfl_xor(lsum[i], off);
      float mn = fmaxf(m[i], om);
      lsum[i] = lsum[i] * __expf(m[i] - mn) + ol * __expf(om - mn);
      m[i] = mn;
    }
  }
  float inv[4];
#pragma unroll
  for (int i = 0; i < 4; ++i) inv[i] = 1.0f / lsum[i];

  // ---- pass 2: P write + PV (K and V staged, double-buffered) ----
  stK(0, 0);
  stV(0, 0);
  __syncthreads();
  f32x4 oacc[4] = {};
  for (int tt = 0; tt <= st; ++tt) {
    const int t0 = tt * 64;
    const int cur = tt & 1;
    if (tt < st) { stK(cur ^ 1, t0 + 64); stV(cur ^ 1, t0 + 64); }
#pragma unroll
    for (int ts = 0; ts < 4; ++ts) {
      s16x8 kf0 = KF(cur, ts * 16 + lr, lg);
      s16x8 kf1 = KF(cur, ts * 16 + lr, 4 + lg);
      f32x4 acc = {};
      acc = MFMA_BF16(qf0, kf0, acc);
      acc = MFMA_BF16(qf1, kf1, acc);
      int tg = t0 + ts * 16 + lr;
#pragma unroll
      for (int i = 0; i < 4; ++i) {
        int sg = s0 + w * 16 + lg * 4 + i;
        float p = (tg <= sg) ? __expf(acc[i] * 0.125f - m[i]) * inv[i] : 0.f;
        attn[(((size_t)b * S_ + sg) * H_ + h) * S_ + tg] = p;
        Pb[w][lg * 4 + i][ts * 16 + lr] = f2bf(p);
      }
    }
    asm volatile("s_waitcnt lgkmcnt(0)" ::: "memory");
    __builtin_amdgcn_sched_barrier(0);
    s16x8 pa0 = *(const s16x8*)(&Pb[w][lr][8 * lg]);
    s16x8 pa1 = *(const s16x8*)(&Pb[w][lr][32 + 8 * lg]);
#pragma unroll
    for (int ds = 0; ds < 4; ++ds) {
      s16x8 vf0 = VF(cur, ds * 16 + lr, lg);
      s16x8 vf1 = VF(cur, ds * 16 + lr, 4 + lg);
      oacc[ds] = MFMA_BF16(pa0, vf0, oacc[ds]);
      oacc[ds] = MFMA_BF16(pa1, vf1, oacc[ds]);
    }
    __syncthreads();
  }

  // ---- causal zerofill for tiles above the diagonal ----
  for (int tt = st + 1; tt < 8; ++tt) {
    const int t0 = tt * 64;
    f32x4 z = {};
#pragma unroll
    for (int i = 0; i < 4; ++i) {
      int sg = s0 + w * 16 + lg * 4 + i;
      *(f32x4*)(attn + (((size_t)b * S_ + sg) * H_ + h) * S_ + t0 + lr * 4) = z;
    }
  }

#pragma unroll
  for (int ds = 0; ds < 4; ++ds) {
#pragma unroll
    for (int i = 0; i < 4; ++i) {
      int s = s0 + w * 16 + lg * 4 + i;
      hh[(((size_t)b * H_ + h) * S_ + s) * DK_ + ds * 16 + lr] = oacc[ds][i];
    }
  }
}

// ---------------------------------------------------------------------------
// mh[b][s][dk] = 0.25 * sum_h hh[b][h][s][dk]  (bf16 out)
// ---------------------------------------------------------------------------
__global__ void mean_kernel(const float* __restrict__ hh, unsigned short* __restrict__ mh) {
  int idx = blockIdx.x * 256 + threadIdx.x;
  int e4 = idx * 4;
  int b = e4 >> 15;
  int rem = e4 & 32767;
  f32x4 sum = {};
#pragma unroll
  for (int h = 0; h < 4; ++h) {
    f32x4 v = *(const f32x4*)(hh + ((size_t)b * H_ + h) * (S_ * DK_) + rem);
    sum += v;
  }
  u16x4 pk;
#pragma unroll
  for (int i = 0; i < 4; ++i) pk[i] = f2bf(sum[i] * 0.25f);
  *(u16x4*)(mh + (size_t)b * (S_ * DK_) + rem) = pk;
}

// ---------------------------------------------------------------------------
// out[m][d] = mh[m][:] . Wh[d][:]  (f32 out), K=64, bf16 MFMA.
// ---------------------------------------------------------------------------
__global__ __launch_bounds__(256) void outproj_kernel(
    const unsigned short* __restrict__ mh, const unsigned short* __restrict__ Whb,
    float* __restrict__ out) {
  const int m0 = blockIdx.x * 64, n0 = blockIdx.y * 64;
  const int tid = threadIdx.x, w = tid >> 6, l = tid & 63;
  const int lr = l & 15, lg = l >> 4;
  s16x8 af0 = *(const s16x8*)(mh + (size_t)(m0 + w * 16 + lr) * DK_ + 8 * lg);
  s16x8 af1 = *(const s16x8*)(mh + (size_t)(m0 + w * 16 + lr) * DK_ + 32 + 8 * lg);
  f32x4 acc[4] = {};
#pragma unroll
  for (int ns = 0; ns < 4; ++ns) {
    const unsigned short* wr = Whb + (size_t)(n0 + ns * 16 + lr) * DK_;
    s16x8 wf0 = *(const s16x8*)(wr + 8 * lg);
    s16x8 wf1 = *(const s16x8*)(wr + 32 + 8 * lg);
    acc[ns] = MFMA_BF16(af0, wf0, acc[ns]);
    acc[ns] = MFMA_BF16(af1, wf1, acc[ns]);
  }
#pragma unroll
  for (int ns = 0; ns < 4; ++ns) {
#pragma unroll
    for (int i = 0; i < 4; ++i) {
      out[(size_t)(m0 + w * 16 + lg * 4 + i) * D_ + n0 + ns * 16 + lr] = acc[ns][i];
    }
  }
}

// ---------------------------------------------------------------------------
extern "C" void kernel_launch(void* const* d_in, const int* in_sizes, int n_in,
                              void* d_out, int out_size, void* d_ws, size_t ws_size,
                              hipStream_t stream) {
  (void)in_sizes; (void)n_in; (void)out_size; (void)ws_size;
  const float* q  = (const float*)d_in[0];
  const float* k  = (const float*)d_in[1];
  const float* v  = (const float*)d_in[2];
  const float* Wq = (const float*)d_in[4];
  const float* bq = (const float*)d_in[5];
  const float* Wk = (const float*)d_in[6];
  const float* bk = (const float*)d_in[7];
  const float* Wv = (const float*)d_in[8];
  const float* bv = (const float*)d_in[9];
  const float* Wh = (const float*)d_in[10];

  float* out  = (float*)d_out;                       // [B,S,D]
  float* attn = out + (size_t)B_ * S_ * D_;          // [B,S,H,S]

  char* ws = (char*)d_ws;
  unsigned short* Wb  = (unsigned short*)ws;                         // 163840 elems
  unsigned short* qs  = (unsigned short*)(ws + 327680);              // [B,H,S,DK] bf16
  unsigned short* ksp = (unsigned short*)(ws + 327680 + 8388608);    // [B,H,S,DK] bf16
  unsigned short* vst = (unsigned short*)(ws + 327680 + 16777216);   // [B,DK,S]  bf16
  float*          hh  = (float*)(ws + 327680 + 18874368);            // [B,H,S,DK] f32
  unsigned short* mh  = (unsigned short*)(ws + 327680 + 35651584);   // [B,S,DK]  bf16

  wconv_kernel<<<640, 256, 0, stream>>>(Wq, Wk, Wv, Wh, Wb);
  proj_kernel<<<dim3(256, 3), 256, 0, stream>>>(q, k, v, Wb, bq, bk, bv, qs, ksp, vst);
  attn_kernel<<<1024, 256, 0, stream>>>(qs, ksp, vst, attn, hh);
  mean_kernel<<<1024, 256, 0, stream>>>(hh, mh);
  outproj_kernel<<<dim3(256, 4), 256, 0, stream>>>(mh, Wb + 147456, out);
}

// Round 6
// 101.800 us; speedup vs baseline: 3.2070x; 1.0395x over previous
//
#include <hip/hip_runtime.h>
#include <math.h>

#define B_  32
#define S_  512
#define D_  256
#define H_  4
#define DK_ 64

typedef float  f32x4 __attribute__((ext_vector_type(4)));
typedef short  s16x8 __attribute__((ext_vector_type(8)));
typedef unsigned short u16x4 __attribute__((ext_vector_type(4)));
typedef unsigned int   u32x4 __attribute__((ext_vector_type(4)));

#define MFMA_BF16(a, b, c) __builtin_amdgcn_mfma_f32_16x16x32_bf16((a), (b), (c), 0, 0, 0)
#define GLOAD_LDS16(g, l)                                                      \
  __builtin_amdgcn_global_load_lds(                                            \
      (const __attribute__((address_space(1))) void*)(g),                      \
      (__attribute__((address_space(3))) void*)(l), 16, 0, 0)

#if __has_builtin(__builtin_amdgcn_exp2f)
#define EXP2(x) __builtin_amdgcn_exp2f(x)
#else
#define EXP2(x) __expf((x) * 0.6931471805599453f)
#endif

// 0.125 * log2(e): folded into Wq/bq so QK^T lands in log2 domain.
#define QSCALE 0.18033688011112042f

__device__ __forceinline__ unsigned short f2bf(float x) {
  unsigned int u = __float_as_uint(x);
  unsigned int r = (u + 0x7FFFu + ((u >> 16) & 1u)) >> 16;
  return (unsigned short)r;
}

__device__ __forceinline__ float bf2f(unsigned short u) {
  return __uint_as_float((unsigned int)u << 16);
}

__device__ __forceinline__ unsigned cvtpk(float lo, float hi) {
  unsigned r;
  asm("v_cvt_pk_bf16_f32 %0, %1, %2" : "=v"(r) : "v"(lo), "v"(hi));
  return r;
}

__device__ __forceinline__ s16x8 cvt8(const float* p) {
  float4 a = *(const float4*)p;
  float4 b = *(const float4*)(p + 4);
  s16x8 r;
  r[0] = (short)f2bf(a.x); r[1] = (short)f2bf(a.y);
  r[2] = (short)f2bf(a.z); r[3] = (short)f2bf(a.w);
  r[4] = (short)f2bf(b.x); r[5] = (short)f2bf(b.y);
  r[6] = (short)f2bf(b.z); r[7] = (short)f2bf(b.w);
  return r;
}

// ---------------------------------------------------------------------------
// Weights -> bf16: rows 0..255 Wq (pre-scaled by QSCALE), 256..511 Wk,
// 512..575 Wv; Wh at 147456 (pre-scaled by 0.25 for the head-mean fold).
// ---------------------------------------------------------------------------
__global__ void wconv_kernel(const float* __restrict__ Wq, const float* __restrict__ Wk,
                             const float* __restrict__ Wv, const float* __restrict__ Wh,
                             unsigned short* __restrict__ out) {
  int i = blockIdx.x * 256 + threadIdx.x;  // 163840 total
  float v, sc = 1.f;
  if (i < 65536)        { v = Wq[i];          sc = QSCALE; }
  else if (i < 131072)  { v = Wk[i - 65536]; }
  else if (i < 147456)  { v = Wv[i - 131072]; }
  else                  { v = Wh[i - 147456]; sc = 0.25f; }
  out[i] = f2bf(v * sc);
}

// ---------------------------------------------------------------------------
// Fused QKV projection, bf16 MFMA.
// y==0: qs (pre-scaled by QSCALE via Wq/bq); y==1: ks; y==2: vst [b][dk][t].
// ---------------------------------------------------------------------------
__global__ __launch_bounds__(256) void proj_kernel(
    const float* __restrict__ q, const float* __restrict__ k, const float* __restrict__ v,
    const unsigned short* __restrict__ Wb,
    const float* __restrict__ bq, const float* __restrict__ bk, const float* __restrict__ bv,
    unsigned short* __restrict__ qs, unsigned short* __restrict__ ks,
    unsigned short* __restrict__ vst) {
  const int y = blockIdx.y;
  const int m0 = blockIdx.x * 64;
  const int b = m0 >> 9, s0 = m0 & (S_ - 1);
  const int tid = threadIdx.x, w = tid >> 6, l = tid & 63;
  const int lr = l & 15, lg = l >> 4;
  const float* src = (y == 0) ? q : (y == 1) ? k : v;
  const float* abase = src + (size_t)(m0 + w * 16 + lr) * D_;

  if (y < 2) {
    const int wrow0 = y * 256;
    f32x4 acc[4][4] = {};
    for (int k0 = 0; k0 < D_; k0 += 32) {
      s16x8 af = cvt8(abase + k0 + 8 * lg);
#pragma unroll
      for (int h = 0; h < 4; ++h) {
#pragma unroll
        for (int ns = 0; ns < 4; ++ns) {
          s16x8 wf = *(const s16x8*)(Wb + (size_t)(wrow0 + h * 64 + ns * 16 + lr) * D_ + k0 + 8 * lg);
          acc[h][ns] = MFMA_BF16(af, wf, acc[h][ns]);
        }
      }
    }
    const float* bias = (y == 0) ? bq : bk;
    const float bsc = (y == 0) ? QSCALE : 1.f;
    unsigned short* dst = (y == 0) ? qs : ks;
#pragma unroll
    for (int h = 0; h < 4; ++h) {
#pragma unroll
      for (int ns = 0; ns < 4; ++ns) {
        int dk = ns * 16 + lr;
        float bb = bias[h * 64 + dk] * bsc;
#pragma unroll
        for (int i = 0; i < 4; ++i) {
          int s = s0 + w * 16 + lg * 4 + i;
          dst[(((size_t)b * H_ + h) * S_ + s) * DK_ + dk] = f2bf(acc[h][ns][i] + bb);
        }
      }
    }
  } else {
    f32x4 acc[4] = {};
    for (int k0 = 0; k0 < D_; k0 += 32) {
      s16x8 af = cvt8(abase + k0 + 8 * lg);
#pragma unroll
      for (int ns = 0; ns < 4; ++ns) {
        s16x8 wf = *(const s16x8*)(Wb + (size_t)(512 + ns * 16 + lr) * D_ + k0 + 8 * lg);
        acc[ns] = MFMA_BF16(af, wf, acc[ns]);
      }
    }
#pragma unroll
    for (int ns = 0; ns < 4; ++ns) {
      int dk = ns * 16 + lr;
      float bb = bv[dk];
      u16x4 pk;
#pragma unroll
      for (int i = 0; i < 4; ++i) pk[i] = f2bf(acc[ns][i] + bb);
      int t = s0 + w * 16 + lg * 4;
      *(u16x4*)(vst + ((size_t)b * DK_ + dk) * S_ + t) = pk;
    }
  }
}

// ---------------------------------------------------------------------------
// Fused scores + softmax + attn-write + PV + causal zerofill.
// No-max softmax in log2 domain.  P repack via the r3-proven path:
// [s][t] padded LDS tile, 16 x ds_write_b16, read back as 2 x ds_read_b128.
// ---------------------------------------------------------------------------
__global__ __launch_bounds__(256) void attn_kernel(
    const unsigned short* __restrict__ qs, const unsigned short* __restrict__ ks,
    const unsigned short* __restrict__ vst, float* __restrict__ attn,
    unsigned short* __restrict__ hh) {
  const int n = blockIdx.x;
  const int b = n & 31, h = (n >> 5) & 3, st = n >> 7;
  const int tid = threadIdx.x, w = tid >> 6, l = tid & 63;
  const int lr = l & 15, lg = l >> 4;
  const int s0 = st * 64;

  __shared__ __align__(16) unsigned short Kb[2][4096];   // 64x64 bf16, swizzled
  __shared__ __align__(16) unsigned short Vb[2][4096];   // [dk][t] bf16, swizzled
  __shared__ __align__(16) unsigned short Pb[4][16][72]; // per-wave P, [s][t]+pad

  const unsigned short* qb = qs + ((size_t)b * H_ + h) * S_ * DK_;
  const char* kbase = (const char*)(ks + ((size_t)b * H_ + h) * S_ * DK_);
  const char* vbase = (const char*)(vst + (size_t)b * DK_ * S_);

  auto stK = [&](int buf, int t0) {
#pragma unroll
    for (int it = 0; it < 2; ++it) {
      int p = it * 4096 + tid * 16;
      int row = p >> 7, c = (p >> 4) & 7;
      GLOAD_LDS16(kbase + (size_t)t0 * 128 + row * 128 + ((c ^ (row & 7)) << 4),
                  (char*)&Kb[buf][0] + p);
    }
  };
  auto stV = [&](int buf, int t0) {
#pragma unroll
    for (int it = 0; it < 2; ++it) {
      int p = it * 4096 + tid * 16;
      int row = p >> 7, c = (p >> 4) & 7;
      GLOAD_LDS16(vbase + (size_t)row * 1024 + t0 * 2 + ((c ^ (row & 7)) << 4),
                  (char*)&Vb[buf][0] + p);
    }
  };
  auto KF = [&](int buf, int row, int c) -> s16x8 {
    return *(const s16x8*)((const char*)&Kb[buf][0] + row * 128 + ((c ^ (row & 7)) << 4));
  };
  auto VF = [&](int buf, int row, int c) -> s16x8 {
    return *(const s16x8*)((const char*)&Vb[buf][0] + row * 128 + ((c ^ (row & 7)) << 4));
  };

  s16x8 qf0 = *(const s16x8*)(qb + (size_t)(s0 + w * 16 + lr) * DK_ + 8 * lg);
  s16x8 qf1 = *(const s16x8*)(qb + (size_t)(s0 + w * 16 + lr) * DK_ + 32 + 8 * lg);

  float lsum[4] = {0.f, 0.f, 0.f, 0.f};

  // ---- pass 1: row sums of exp2(sc) (no max tracking) ----
  stK(0, 0);
  __syncthreads();
  for (int tt = 0; tt <= st; ++tt) {
    const int cur = tt & 1;
    if (tt < st) stK(cur ^ 1, tt * 64 + 64);
#pragma unroll
    for (int ts = 0; ts < 4; ++ts) {
      s16x8 kf0 = KF(cur, ts * 16 + lr, lg);
      s16x8 kf1 = KF(cur, ts * 16 + lr, 4 + lg);
      f32x4 acc = {};
      acc = MFMA_BF16(qf0, kf0, acc);
      acc = MFMA_BF16(qf1, kf1, acc);
      if (tt == st) {  // diagonal tile: causal mask
        int tg = tt * 64 + ts * 16 + lr;
#pragma unroll
        for (int i = 0; i < 4; ++i) {
          int sg = s0 + w * 16 + lg * 4 + i;
          lsum[i] += EXP2((tg > sg) ? -1e30f : acc[i]);
        }
      } else {
#pragma unroll
        for (int i = 0; i < 4; ++i) lsum[i] += EXP2(acc[i]);
      }
    }
    __syncthreads();
  }
  // cross-lane sum within 16-lane groups
#pragma unroll
  for (int off = 1; off < 16; off <<= 1) {
#pragma unroll
    for (int i = 0; i < 4; ++i) lsum[i] += __shfl_xor(lsum[i], off);
  }
  float lg2s[4];
#pragma unroll
  for (int i = 0; i < 4; ++i) lg2s[i] = __log2f(lsum[i]);

  // ---- pass 2: P write + PV ----
  stK(0, 0);
  stV(0, 0);
  __syncthreads();
  f32x4 oacc[4] = {};
  for (int tt = 0; tt <= st; ++tt) {
    const int t0 = tt * 64;
    const int cur = tt & 1;
    if (tt < st) { stK(cur ^ 1, t0 + 64); stV(cur ^ 1, t0 + 64); }
#pragma unroll
    for (int ts = 0; ts < 4; ++ts) {
      s16x8 kf0 = KF(cur, ts * 16 + lr, lg);
      s16x8 kf1 = KF(cur, ts * 16 + lr, 4 + lg);
      f32x4 acc = {};
      acc = MFMA_BF16(qf0, kf0, acc);
      acc = MFMA_BF16(qf1, kf1, acc);
      int tg = t0 + ts * 16 + lr;
      float p[4];
      if (tt == st) {
#pragma unroll
        for (int i = 0; i < 4; ++i) {
          int sg = s0 + w * 16 + lg * 4 + i;
          p[i] = EXP2(((tg > sg) ? -1e30f : acc[i]) - lg2s[i]);
        }
      } else {
#pragma unroll
        for (int i = 0; i < 4; ++i) p[i] = EXP2(acc[i] - lg2s[i]);
      }
#pragma unroll
      for (int i = 0; i < 4; ++i) {
        int sg = s0 + w * 16 + lg * 4 + i;
        attn[(((size_t)b * S_ + sg) * H_ + h) * S_ + tg] = p[i];
      }
      unsigned pk0 = cvtpk(p[0], p[1]);
      unsigned pk1 = cvtpk(p[2], p[3]);
      Pb[w][lg * 4 + 0][ts * 16 + lr] = (unsigned short)pk0;
      Pb[w][lg * 4 + 1][ts * 16 + lr] = (unsigned short)(pk0 >> 16);
      Pb[w][lg * 4 + 2][ts * 16 + lr] = (unsigned short)pk1;
      Pb[w][lg * 4 + 3][ts * 16 + lr] = (unsigned short)(pk1 >> 16);
    }
    asm volatile("s_waitcnt lgkmcnt(0)" ::: "memory");
    __builtin_amdgcn_sched_barrier(0);
    s16x8 pa0 = *(const s16x8*)(&Pb[w][lr][8 * lg]);
    s16x8 pa1 = *(const s16x8*)(&Pb[w][lr][32 + 8 * lg]);
#pragma unroll
    for (int ds = 0; ds < 4; ++ds) {
      s16x8 vf0 = VF(cur, ds * 16 + lr, lg);
      s16x8 vf1 = VF(cur, ds * 16 + lr, 4 + lg);
      oacc[ds] = MFMA_BF16(pa0, vf0, oacc[ds]);
      oacc[ds] = MFMA_BF16(pa1, vf1, oacc[ds]);
    }
    __syncthreads();
  }

  // ---- causal zerofill above the diagonal ----
  for (int tt = st + 1; tt < 8; ++tt) {
    const int t0 = tt * 64;
    f32x4 z = {};
#pragma unroll
    for (int i = 0; i < 4; ++i) {
      int sg = s0 + w * 16 + lg * 4 + i;
      *(f32x4*)(attn + (((size_t)b * S_ + sg) * H_ + h) * S_ + t0 + lr * 4) = z;
    }
  }

  // ---- per-head output (bf16) ----
#pragma unroll
  for (int ds = 0; ds < 4; ++ds) {
#pragma unroll
    for (int i = 0; i < 4; ++i) {
      int s = s0 + w * 16 + lg * 4 + i;
      hh[(((size_t)b * H_ + h) * S_ + s) * DK_ + ds * 16 + lr] = f2bf(oacc[ds][i]);
    }
  }
}

// ---------------------------------------------------------------------------
// Fused head-mean + output projection: out[m][n] = (sum_h hh[b][h][s][:]) . Whb[n][:]
// (0.25 head-mean folded into Whb — exact, power of 2).
// ---------------------------------------------------------------------------
__global__ __launch_bounds__(256) void houtproj_kernel(
    const unsigned short* __restrict__ hh, const unsigned short* __restrict__ Whb,
    float* __restrict__ out) {
  const int m0 = blockIdx.x * 64, n0 = blockIdx.y * 64;
  const int tid = threadIdx.x, w = tid >> 6, l = tid & 63;
  const int lr = l & 15, lg = l >> 4;
  const int row = m0 + w * 16 + lr;
  const int b = row >> 9, s = row & (S_ - 1);

  s16x8 af[2];
#pragma unroll
  for (int kk = 0; kk < 2; ++kk) {
    float sum8[8] = {};
#pragma unroll
    for (int hd = 0; hd < 4; ++hd) {
      s16x8 x = *(const s16x8*)(hh + (((size_t)b * H_ + hd) * S_ + s) * DK_ + kk * 32 + 8 * lg);
#pragma unroll
      for (int e = 0; e < 8; ++e) sum8[e] += bf2f((unsigned short)x[e]);
    }
    u32x4 pk;
#pragma unroll
    for (int j = 0; j < 4; ++j) pk[j] = cvtpk(sum8[2 * j], sum8[2 * j + 1]);
    af[kk] = *(s16x8*)&pk;
  }
  f32x4 acc[4] = {};
#pragma unroll
  for (int ns = 0; ns < 4; ++ns) {
    const unsigned short* wr = Whb + (size_t)(n0 + ns * 16 + lr) * DK_;
    s16x8 wf0 = *(const s16x8*)(wr + 8 * lg);
    s16x8 wf1 = *(const s16x8*)(wr + 32 + 8 * lg);
    acc[ns] = MFMA_BF16(af[0], wf0, acc[ns]);
    acc[ns] = MFMA_BF16(af[1], wf1, acc[ns]);
  }
#pragma unroll
  for (int ns = 0; ns < 4; ++ns) {
#pragma unroll
    for (int i = 0; i < 4; ++i) {
      out[(size_t)(m0 + w * 16 + lg * 4 + i) * D_ + n0 + ns * 16 + lr] = acc[ns][i];
    }
  }
}

// ---------------------------------------------------------------------------
extern "C" void kernel_launch(void* const* d_in, const int* in_sizes, int n_in,
                              void* d_out, int out_size, void* d_ws, size_t ws_size,
                              hipStream_t stream) {
  (void)in_sizes; (void)n_in; (void)out_size; (void)ws_size;
  const float* q  = (const float*)d_in[0];
  const float* k  = (const float*)d_in[1];
  const float* v  = (const float*)d_in[2];
  const float* Wq = (const float*)d_in[4];
  const float* bq = (const float*)d_in[5];
  const float* Wk = (const float*)d_in[6];
  const float* bk = (const float*)d_in[7];
  const float* Wv = (const float*)d_in[8];
  const float* bv = (const float*)d_in[9];
  const float* Wh = (const float*)d_in[10];

  float* out  = (float*)d_out;                       // [B,S,D]
  float* attn = out + (size_t)B_ * S_ * D_;          // [B,S,H,S]

  char* ws = (char*)d_ws;
  unsigned short* Wb  = (unsigned short*)ws;                         // 163840 elems
  unsigned short* qs  = (unsigned short*)(ws + 327680);              // [B,H,S,DK] bf16
  unsigned short* ksp = (unsigned short*)(ws + 327680 + 8388608);    // [B,H,S,DK] bf16
  unsigned short* vst = (unsigned short*)(ws + 327680 + 16777216);   // [B,DK,S]  bf16
  unsigned short* hh  = (unsigned short*)(ws + 327680 + 18874368);   // [B,H,S,DK] bf16

  wconv_kernel<<<640, 256, 0, stream>>>(Wq, Wk, Wv, Wh, Wb);
  proj_kernel<<<dim3(256, 3), 256, 0, stream>>>(q, k, v, Wb, bq, bk, bv, qs, ksp, vst);
  attn_kernel<<<1024, 256, 0, stream>>>(qs, ksp, vst, attn, hh);
  houtproj_kernel<<<dim3(256, 4), 256, 0, stream>>>(hh, Wb + 147456, out);
}